// Round 10
// baseline (31.015 us; speedup 1.0000x reference)
//
#include <hip/hip_runtime.h>

#define BB 16
#define NL 60
#define NA 3
#define NC 80
#define BS 256

// blocks per batch: 34(s0)+9(s1)+3(s2) cell blocks (2 cells/thread, 256 thr) + 1 target
#define NBX0C 34
#define NBX1C 9
#define NBX2C 3
#define NBXC  (NBX0C+NBX1C+NBX2C)   // 46
#define NBX   (NBXC+1)              // 47
#define TOTAL_BLOCKS (NBX*BB)       // 752

__device__ __constant__ float d_AW[9] = {12.f,19.f,40.f,36.f,76.f,72.f,142.f,192.f,459.f};
__device__ __constant__ float d_AH[9] = {16.f,36.f,28.f,75.f,55.f,146.f,110.f,243.f,401.f};

__device__ __forceinline__ float sig_pos(float v){ return __fdividef(1.0f, 1.0f + __expf(-v)); }
__device__ __forceinline__ float sig_neg(float v){ return __fdividef(1.0f, 1.0f + __expf(v)); }
__device__ __forceinline__ float bcef(float p, float t){
    float lp  = __logf(fmaxf(p, 1e-12f));
    float l1p = __logf(1.0f - fminf(p, 1.0f - 1e-7f));
    return -(t*lp + (1.0f - t)*l1p);
}

// ---- issue the channel loads EARLY (before prep+barrier) ----
template<int SID>
__device__ __forceinline__ bool cell_load(const float* __restrict__ raw, int xoff, int b, int tid,
        int &a, int &rembase, int &nc,
        float (&cx)[2], float (&cy)[2], float (&cw)[2], float (&ch)[2], float (&co)[2])
{
    constexpr int F  = (SID==0)?76:(SID==1)?38:19;
    constexpr int FF = F*F;
    int t = xoff*BS + tid;
    if (SID < 2){
        constexpr int NT = 3*FF/2;           // FF divisible by 2 for s0/s1
        if (t >= NT) return false;
        a = t / (FF/2);
        rembase = 2*t - a*FF;
        nc = 2;
        const float* base = raw + ((size_t)(b*(NA*85) + a*85))*FF + rembase;
        float2 q0 = *reinterpret_cast<const float2*>(base);
        float2 q1 = *reinterpret_cast<const float2*>(base +   (size_t)FF);
        float2 q2 = *reinterpret_cast<const float2*>(base + 2*(size_t)FF);
        float2 q3 = *reinterpret_cast<const float2*>(base + 3*(size_t)FF);
        float2 q4 = *reinterpret_cast<const float2*>(base + 4*(size_t)FF);
        cx[0]=q0.x; cx[1]=q0.y;
        cy[0]=q1.x; cy[1]=q1.y;
        cw[0]=q2.x; cw[1]=q2.y;
        ch[0]=q3.x; ch[1]=q3.y;
        co[0]=q4.x; co[1]=q4.y;
    } else {
        constexpr int GPA = (FF+1)/2;        // 181 groups per anchor (361 cells)
        if (t >= 3*GPA) return false;
        a = t / GPA;
        int k = t - a*GPA;
        rembase = 2*k;
        nc = (FF - rembase < 2) ? (FF - rembase) : 2;
        const float* base = raw + ((size_t)(b*(NA*85) + a*85))*FF + rembase;
        #pragma unroll
        for (int c=0;c<2;c++){
            bool v = c < nc;
            cx[c] = v ? base[c]              : 0.f;
            cy[c] = v ? base[(size_t)FF+c]   : 0.f;
            cw[c] = v ? base[2*(size_t)FF+c] : 0.f;
            ch[c] = v ? base[3*(size_t)FF+c] : 0.f;
            co[c] = v ? base[4*(size_t)FF+c] : 0.f;
        }
    }
    return true;
}

template<int SID>
__device__ __forceinline__ void cell_compute(int a, int rembase, int nc,
        const float (&cx)[2], const float (&cy)[2], const float (&cw)[2],
        const float (&ch)[2], const float (&co)[2],
        const float4* s_bxc, const float* s_at3c, int nbx,
        const int* s_used, int nuse,
        float &lob, float &l2)
{
    constexpr int   F   = (SID==0)?76:(SID==1)?38:19;
    constexpr int   FF  = F*F;
    constexpr float RST = (SID==0)?0.125f:(SID==1)?0.0625f:0.03125f;
    float aw = d_AW[SID*3+a]*RST, ah = d_AH[SID*3+a]*RST;
    float plox[2],phix[2],ploy[2],phiy[2],ap3[2];
    #pragma unroll
    for (int c=0;c<2;c++){
        int cel = rembase + c;
        int j = cel / F;                 // compile-time divisor
        int i = cel - j*F;
        float x = sig_pos(cx[c]), y = sig_pos(cy[c]);
        float pw = __expf(cw[c])*aw, ph = __expf(ch[c])*ah;
        float px = x + (float)i, py = y + (float)j;
        float hx = 0.5f*pw, hy = 0.5f*ph;
        plox[c]=px-hx; phix[c]=px+hx; ploy[c]=py-hy; phiy[c]=py+hy;
        ap3[c]=pw*ph*(1.0f/3.0f);
    }
    bool skip0=false, skip1=false;
    #pragma unroll 2
    for (int l=0;l<nbx;l++){             // compacted: valid labels only
        float4 bb = s_bxc[l];
        float thr = s_at3c[l];
        float iw0 = fminf(phix[0],bb.y)-fmaxf(plox[0],bb.x);
        float ih0 = fminf(phiy[0],bb.w)-fmaxf(ploy[0],bb.z);
        float iw1 = fminf(phix[1],bb.y)-fmaxf(plox[1],bb.x);
        float ih1 = fminf(phiy[1],bb.w)-fmaxf(ploy[1],bb.z);
        skip0 = skip0 || (fmaxf(iw0,0.f)*fmaxf(ih0,0.f) > ap3[0]+thr);
        skip1 = skip1 || (fmaxf(iw1,0.f)*fmaxf(ih1,0.f) > ap3[1]+thr);
    }
    int cellbase = a*FF + rembase;
    for (int k=0;k<nuse;k++){
        int uc = s_used[k];
        skip0 = skip0 || (uc==cellbase);
        skip1 = skip1 || (uc==cellbase+1);
    }
    #pragma unroll
    for (int c=0;c<2;c++){
        bool sk = (c==0)?skip0:skip1;
        if (c < nc && !sk){
            float snb = sig_neg(co[c]);
            lob += -__logf(fmaxf(snb,1e-7f));
            float ob = 1.0f - snb;
            l2 += ob*ob;
        }
    }
}

__global__ __launch_bounds__(BS) void fused_kernel(
        const float* __restrict__ x0, const float* __restrict__ x1,
        const float* __restrict__ x2, const float* __restrict__ labels,
        float* __restrict__ part)
{
    __shared__ float4 s_bxc[NL];        // cell blocks: compacted valid boxes
    __shared__ float  s_at3c[NL];
    __shared__ int    s_used[NL];
    __shared__ int    s_nuse, s_nbx, s_ntgt;
    __shared__ int    s_code3[3][NL];   // target block: rr | bn<<18 | cls<<20
    __shared__ float  s_tv3[3][NL][5];
    __shared__ int    s_tinfo[NL];      // compacted: rr | aa<<13 | sd<<15 | l<<17
    __shared__ unsigned long long s_tm0[NL], s_tm1[NL];
    __shared__ float  red[5][4];

    const int tid = threadIdx.x;
    const int bxi = blockIdx.x;
    const int b   = blockIdx.y;

    int sid, xoff, tgtblk;
    if      (bxi < NBX0C)       { sid = 0; xoff = bxi;               tgtblk = 0; }
    else if (bxi < NBX0C+NBX1C) { sid = 1; xoff = bxi-NBX0C;         tgtblk = 0; }
    else if (bxi < NBXC)        { sid = 2; xoff = bxi-(NBX0C+NBX1C); tgtblk = 0; }
    else                        { sid = 0; xoff = 0;                 tgtblk = 1; }

    // ---- issue cell loads before prep so latency hides under prep+barrier ----
    float cx[2],cy[2],cw[2],chn[2],co[2];
    int a=0, rembase=0, nc=0;
    bool active=false;
    if (!tgtblk){
        const float* raw = (sid==0)?x0:(sid==1)?x1:x2;
        if      (sid==0) active = cell_load<0>(raw,xoff,b,tid,a,rembase,nc,cx,cy,cw,chn,co);
        else if (sid==1) active = cell_load<1>(raw,xoff,b,tid,a,rembase,nc,cx,cy,cw,chn,co);
        else             active = cell_load<2>(raw,xoff,b,tid,a,rembase,nc,cx,cy,cw,chn,co);
    }

    if (tid == 0){ s_nuse = 0; s_nbx = 0; s_ntgt = 0; }
    __syncthreads();

    if (!tgtblk){
        // ---- cell-block prep: compacted boxes + used-cell list (own scale) ----
        if (tid < NL){
            const float RSTv = (sid==0)?0.125f:(sid==1)?0.0625f:0.03125f;
            const int   F    = (sid==0)?76:(sid==1)?38:19;
            const float* lb = labels + ((size_t)b*NL + tid)*5;
            float x1f=lb[0], y1f=lb[1], x2f=lb[2], y2f=lb[3], cl=lb[4];
            bool valid = (x1f+y1f+x2f+y2f+cl) > 0.0f;
            float tx=(x1f+x2f)*0.5f*RSTv, ty=(y1f+y2f)*0.5f*RSTv;
            float tw=(x2f-x1f)*RSTv, th=(y2f-y1f)*RSTv;
            float at=tw*th;
            float best=-1.0f; int bi=0;
            #pragma unroll
            for (int k=0;k<9;k++){
                float rw=d_AW[k]*RSTv, rh=d_AH[k]*RSTv;
                float mw=fminf(tw,rw), mh=fminf(th,rh);
                float inter=(mw>0.f && mh>0.f)? mw*mh : 0.f;
                float aiou = inter/(at + rw*rh - inter);
                if (aiou > best){ best=aiou; bi=k; }   // first-max = jnp.argmax
            }
            if (valid){
                int p = atomicAdd(&s_nbx, 1);
                float htw=0.5f*tw, hth=0.5f*th;
                s_bxc[p]  = make_float4(tx-htw, tx+htw, ty-hth, ty+hth);
                s_at3c[p] = at*(1.0f/3.0f);
            }
            if (valid && (bi/3 == sid)){
                int bn = bi%3;
                int ii=(int)tx, jj=(int)ty;
                int p = atomicAdd(&s_nuse, 1);
                s_used[p] = (bn*F + jj)*F + ii;       // existence-only
            }
        }
    } else {
        // ---- target-block prep 1: codes + t-values for ALL 3 scales ----
        if (tid < 3*NL){
            int sd = tid/NL, l = tid - sd*NL;
            const float RSTv = (sd==0)?0.125f:(sd==1)?0.0625f:0.03125f;
            const int   F    = (sd==0)?76:(sd==1)?38:19;
            const int   FF   = F*F;
            const float* lb = labels + ((size_t)b*NL + l)*5;
            float x1f=lb[0], y1f=lb[1], x2f=lb[2], y2f=lb[3], cl=lb[4];
            bool valid = (x1f+y1f+x2f+y2f+cl) > 0.0f;
            float tx=(x1f+x2f)*0.5f*RSTv, ty=(y1f+y2f)*0.5f*RSTv;
            float tw=(x2f-x1f)*RSTv, th=(y2f-y1f)*RSTv;
            float at=tw*th;
            float best=-1.0f; int bi=0;
            #pragma unroll
            for (int k=0;k<9;k++){
                float rw=d_AW[k]*RSTv, rh=d_AH[k]*RSTv;
                float mw=fminf(tw,rw), mh=fminf(th,rh);
                float inter=(mw>0.f && mh>0.f)? mw*mh : 0.f;
                float aiou = inter/(at + rw*rh - inter);
                if (aiou > best){ best=aiou; bi=k; }
            }
            int bn = bi%3;
            bool use = valid && (bi/3 == sd);
            int ii=(int)tx, jj=(int)ty;
            int rr = jj*F + ii;                       // in-anchor cell
            s_code3[sd][l] = use ? (rr | (bn<<18) | (((int)cl)<<20)) : -1;
            float aw=d_AW[sd*3+bn]*RSTv, ah=d_AH[sd*3+bn]*RSTv;
            s_tv3[sd][l][0]=tx-(float)ii;
            s_tv3[sd][l][1]=ty-(float)jj;
            s_tv3[sd][l][2]=__logf(__fdividef(tw,aw) + 1e-16f);
            s_tv3[sd][l][3]=__logf(__fdividef(th,ah) + 1e-16f);
            s_tv3[sd][l][4]=sqrtf(2.0f - at/(float)FF);
        }
        __syncthreads();
        // ---- target-block prep 2: owner + class-mask per used cell, compacted ----
        if (tid < 3*NL){
            int sd = tid/NL, l = tid - sd*NL;
            int cd = s_code3[sd][l];
            if (cd >= 0){
                int tcell = cd & 0xFFFFF;             // rr | bn<<18
                int last = -1;
                unsigned long long cm0=0ull, cm1=0ull;
                for (int q=0;q<NL;q++){
                    int cq = s_code3[sd][q];
                    if (cq>=0 && (cq&0xFFFFF)==tcell){
                        last = q; int cc = cq>>20;
                        if (cc<64) cm0 |= 1ull<<cc; else cm1 |= 1ull<<(cc-64);
                    }
                }
                if (last == l){                       // single owner per cell
                    int p = atomicAdd(&s_ntgt, 1);
                    int rr = cd & 0x3FFFF, aa = (cd>>18)&3;
                    s_tinfo[p] = rr | (aa<<13) | (sd<<15) | (l<<17);
                    s_tm0[p] = cm0; s_tm1[p] = cm1;
                }
            }
        }
    }
    __syncthreads();

    float lxy=0.f, lwh=0.f, lob=0.f, lcl=0.f, l2=0.f;

    if (!tgtblk){
        if (active){
            int nuse = s_nuse, nbx = s_nbx;
            if      (sid==0) cell_compute<0>(a,rembase,nc,cx,cy,cw,chn,co,s_bxc,s_at3c,nbx,s_used,nuse,lob,l2);
            else if (sid==1) cell_compute<1>(a,rembase,nc,cx,cy,cw,chn,co,s_bxc,s_at3c,nbx,s_used,nuse,lob,l2);
            else             cell_compute<2>(a,rembase,nc,cx,cy,cw,chn,co,s_bxc,s_at3c,nbx,s_used,nuse,lob,l2);
        }
    } else {
        // ---- compacted target pass (4 waves x 12 slices): prefetch all, then process ----
        const int wv = tid>>6, lane = tid&63;
        const int ntgt = s_ntgt;                     // <= 45
        float P1[12], P2[12], E[12];
        int   info[12];
        #pragma unroll
        for (int kk=0; kk<12; kk++){
            int k = wv + kk*4;
            P1[kk]=0.f; P2[kk]=0.f; E[kk]=0.f; info[kk]=-1;
            if (k < ntgt){
                int in = s_tinfo[k];
                info[kk] = in;
                int rr = in & 0x1FFF, aa = (in>>13)&3, sd = (in>>15)&3;
                const float* raw = (sd==0)?x0:(sd==1)?x1:x2;
                int FF = (sd==0)?5776:(sd==1)?1444:361;
                const float* cb = raw + ((size_t)(b*(NA*85) + aa*85))*FF + rr;
                P1[kk] = cb[(size_t)(5+lane)*FF];
                if (lane < 16) P2[kk] = cb[(size_t)(69+lane)*FF];
                if (lane <  5) E[kk]  = cb[(size_t)lane*FF];
            }
        }
        #pragma unroll
        for (int kk=0; kk<12; kk++){
            int in = info[kk];
            if (in < 0) continue;                    // wave-uniform
            int k  = wv + kk*4;
            int l  = (in>>17)&63, sd = (in>>15)&3;
            unsigned long long cm0 = s_tm0[k], cm1 = s_tm1[k];
            float e0=__shfl(E[kk],0), e1=__shfl(E[kk],1), e2=__shfl(E[kk],2),
                  e3=__shfl(E[kk],3), e4=__shfl(E[kk],4);
            float p1 = sig_pos(P1[kk]);
            float t1v = (((cm0>>lane)&1ull)!=0ull) ? 1.f : 0.f;
            lcl += bcef(p1, t1v);
            float d1 = p1 - t1v; l2 += d1*d1;
            if (lane < 16){
                float p2 = sig_pos(P2[kk]);
                float t2v = (((cm1>>lane)&1ull)!=0ull) ? 1.f : 0.f;
                lcl += bcef(p2, t2v);
                float d2 = p2 - t2v; l2 += d2*d2;
            }
            if (lane == 0){
                float xx=sig_pos(e0), yy=sig_pos(e1), ob=sig_pos(e4);
                float t0=s_tv3[sd][l][0], t1=s_tv3[sd][l][1], t2=s_tv3[sd][l][2],
                      t3=s_tv3[sd][l][3], sc=s_tv3[sd][l][4];
                lxy += sc*sc*(bcef(xx,t0)+bcef(yy,t1));
                float d0=(e2-t2)*sc, dd=(e3-t3)*sc;
                lwh += 0.5f*(d0*d0+dd*dd);
                lob += -__logf(fmaxf(ob,1e-12f));
                float dx=xx-t0, dy=yy-t1, dob=ob-1.f;
                l2  += dx*dx+dy*dy+d0*d0+dd*dd+dob*dob;
            }
        }
    }

    // ---- block reduce (4 waves) -> plain store of this block's 5 partials ----
    float v0=lxy, v1=lwh, v2=lob, v3=lcl, v4=l2;
    #pragma unroll
    for (int off=32; off>0; off>>=1){
        v0 += __shfl_down(v0, off, 64);
        v1 += __shfl_down(v1, off, 64);
        v2 += __shfl_down(v2, off, 64);
        v3 += __shfl_down(v3, off, 64);
        v4 += __shfl_down(v4, off, 64);
    }
    if ((tid & 63) == 0){
        int w = tid >> 6;
        red[0][w]=v0; red[1][w]=v1; red[2][w]=v2; red[3][w]=v3; red[4][w]=v4;
    }
    __syncthreads();
    if (tid == 0){
        int slot = b*NBX + bxi;
        #pragma unroll
        for (int c=0;c<5;c++){
            part[c*TOTAL_BLOCKS + slot] = red[c][0]+red[c][1]+red[c][2]+red[c][3];
        }
    }
}

// ---------------- final reduction: 752 partials x 5 comps (kernel boundary = coherence) ----
__global__ __launch_bounds__(256) void fin_kernel(const float* __restrict__ part,
                                                  float* __restrict__ out)
{
    __shared__ double red[5][4];
    int tid = threadIdx.x;
    double v[5] = {0,0,0,0,0};
    for (int i = tid; i < TOTAL_BLOCKS; i += 256){
        #pragma unroll
        for (int c=0;c<5;c++) v[c] += (double)part[c*TOTAL_BLOCKS + i];
    }
    #pragma unroll
    for (int off=32; off>0; off>>=1){
        #pragma unroll
        for (int c=0;c<5;c++) v[c] += __shfl_down(v[c], off, 64);
    }
    if ((tid & 63) == 0){
        int w = tid >> 6;
        #pragma unroll
        for (int c=0;c<5;c++) red[c][w] = v[c];
    }
    __syncthreads();
    if (tid == 0){
        double lxy = red[0][0]+red[0][1]+red[0][2]+red[0][3];
        double lwh = red[1][0]+red[1][1]+red[1][2]+red[1][3];
        double lob = red[2][0]+red[2][1]+red[2][2]+red[2][3];
        double lcl = red[3][0]+red[3][1]+red[3][2]+red[3][3];
        double l2  = red[4][0]+red[4][1]+red[4][2]+red[4][3];
        out[0]=(float)(lxy+lwh+lob+lcl);
        out[1]=(float)lxy; out[2]=(float)lwh; out[3]=(float)lob;
        out[4]=(float)lcl; out[5]=(float)l2;
    }
}

extern "C" void kernel_launch(void* const* d_in, const int* in_sizes, int n_in,
                              void* d_out, int out_size, void* d_ws, size_t ws_size,
                              hipStream_t stream) {
    const float* x0     = (const float*)d_in[0];
    const float* x1     = (const float*)d_in[1];
    const float* x2     = (const float*)d_in[2];
    const float* labels = (const float*)d_in[3];
    float* out = (float*)d_out;

    float* part = (float*)d_ws;   // 5*752*4 = 15040 B, plain-stored each call

    fused_kernel<<<dim3(NBX, BB), BS, 0, stream>>>(x0, x1, x2, labels, part);
    fin_kernel<<<1, 256, 0, stream>>>(part, out);
}

// Round 11
// 26.100 us; speedup vs baseline: 1.1883x; 1.1883x over previous
//
#include <hip/hip_runtime.h>

#define BB 16
#define NL 60
#define NA 3
#define NC 80
#define BS 512

// blocks per batch: 9(s0)+3(s1)+1(s2) cell blocks (4 cells/thread, 512 thr) + 1 target
#define NBX0C 9
#define NBX1C 3
#define NBX2C 1
#define NBXC  (NBX0C+NBX1C+NBX2C)   // 13
#define NBX   (NBXC+1)              // 14
#define TOTAL_BLOCKS (NBX*BB)       // 224

__device__ __constant__ float d_AW[9] = {12.f,19.f,40.f,36.f,76.f,72.f,142.f,192.f,459.f};
__device__ __constant__ float d_AH[9] = {16.f,36.f,28.f,75.f,55.f,146.f,110.f,243.f,401.f};

__device__ __forceinline__ float sig_pos(float v){ return __fdividef(1.0f, 1.0f + __expf(-v)); }
__device__ __forceinline__ float sig_neg(float v){ return __fdividef(1.0f, 1.0f + __expf(v)); }
__device__ __forceinline__ float bcef(float p, float t){
    float lp  = __logf(fmaxf(p, 1e-12f));
    float l1p = __logf(1.0f - fminf(p, 1.0f - 1e-7f));
    return -(t*lp + (1.0f - t)*l1p);
}

// ---- issue the channel loads EARLY (before prep+barrier) ----
template<int SID>
__device__ __forceinline__ bool cell_load(const float* __restrict__ raw, int xoff, int b, int tid,
        int &a, int &rembase, int &nc,
        float (&cx)[4], float (&cy)[4], float (&cw)[4], float (&ch)[4], float (&co)[4])
{
    constexpr int F  = (SID==0)?76:(SID==1)?38:19;
    constexpr int FF = F*F;
    int t = xoff*BS + tid;
    if (SID < 2){
        constexpr int NT = 3*FF/4;           // FF divisible by 4 for s0/s1
        if (t >= NT) return false;
        a = t / (FF/4);
        rembase = 4*t - a*FF;
        nc = 4;
        const float* base = raw + ((size_t)(b*(NA*85) + a*85))*FF + rembase;
        float4 q0 = *reinterpret_cast<const float4*>(base);
        float4 q1 = *reinterpret_cast<const float4*>(base +   (size_t)FF);
        float4 q2 = *reinterpret_cast<const float4*>(base + 2*(size_t)FF);
        float4 q3 = *reinterpret_cast<const float4*>(base + 3*(size_t)FF);
        float4 q4 = *reinterpret_cast<const float4*>(base + 4*(size_t)FF);
        cx[0]=q0.x; cx[1]=q0.y; cx[2]=q0.z; cx[3]=q0.w;
        cy[0]=q1.x; cy[1]=q1.y; cy[2]=q1.z; cy[3]=q1.w;
        cw[0]=q2.x; cw[1]=q2.y; cw[2]=q2.z; cw[3]=q2.w;
        ch[0]=q3.x; ch[1]=q3.y; ch[2]=q3.z; ch[3]=q3.w;
        co[0]=q4.x; co[1]=q4.y; co[2]=q4.z; co[3]=q4.w;
    } else {
        constexpr int GPA = (FF+3)/4;        // 91 groups per anchor (361 cells)
        if (t >= 3*GPA) return false;
        a = t / GPA;
        int k = t - a*GPA;
        rembase = 4*k;
        nc = (FF - rembase < 4) ? (FF - rembase) : 4;
        const float* base = raw + ((size_t)(b*(NA*85) + a*85))*FF + rembase;
        #pragma unroll
        for (int c=0;c<4;c++){
            bool v = c < nc;
            cx[c] = v ? base[c]              : 0.f;
            cy[c] = v ? base[(size_t)FF+c]   : 0.f;
            cw[c] = v ? base[2*(size_t)FF+c] : 0.f;
            ch[c] = v ? base[3*(size_t)FF+c] : 0.f;
            co[c] = v ? base[4*(size_t)FF+c] : 0.f;
        }
    }
    return true;
}

template<int SID>
__device__ __forceinline__ void cell_compute(int a, int rembase, int nc,
        const float (&cx)[4], const float (&cy)[4], const float (&cw)[4],
        const float (&ch)[4], const float (&co)[4],
        const float4* s_bxc, const float* s_at3c, int nbx,
        const int* s_used, int nuse,
        float &lob, float &l2)
{
    constexpr int   F   = (SID==0)?76:(SID==1)?38:19;
    constexpr int   FF  = F*F;
    constexpr float RST = (SID==0)?0.125f:(SID==1)?0.0625f:0.03125f;
    float aw = d_AW[SID*3+a]*RST, ah = d_AH[SID*3+a]*RST;
    float plox[4],phix[4],ploy[4],phiy[4],ap3[4];
    #pragma unroll
    for (int c=0;c<4;c++){
        int cel = rembase + c;
        int j = cel / F;                 // compile-time divisor
        int i = cel - j*F;
        float x = sig_pos(cx[c]), y = sig_pos(cy[c]);
        float pw = __expf(cw[c])*aw, ph = __expf(ch[c])*ah;
        float px = x + (float)i, py = y + (float)j;
        float hx = 0.5f*pw, hy = 0.5f*ph;
        plox[c]=px-hx; phix[c]=px+hx; ploy[c]=py-hy; phiy[c]=py+hy;
        ap3[c]=pw*ph*(1.0f/3.0f);
    }
    bool skip0=false, skip1=false, skip2=false, skip3=false;
    #pragma unroll 2
    for (int l=0;l<nbx;l++){             // compacted: valid labels only
        float4 bb = s_bxc[l];
        float thr = s_at3c[l];
        float iw0 = fminf(phix[0],bb.y)-fmaxf(plox[0],bb.x);
        float ih0 = fminf(phiy[0],bb.w)-fmaxf(ploy[0],bb.z);
        float iw1 = fminf(phix[1],bb.y)-fmaxf(plox[1],bb.x);
        float ih1 = fminf(phiy[1],bb.w)-fmaxf(ploy[1],bb.z);
        float iw2 = fminf(phix[2],bb.y)-fmaxf(plox[2],bb.x);
        float ih2 = fminf(phiy[2],bb.w)-fmaxf(ploy[2],bb.z);
        float iw3 = fminf(phix[3],bb.y)-fmaxf(plox[3],bb.x);
        float ih3 = fminf(phiy[3],bb.w)-fmaxf(ploy[3],bb.z);
        skip0 = skip0 || (fmaxf(iw0,0.f)*fmaxf(ih0,0.f) > ap3[0]+thr);
        skip1 = skip1 || (fmaxf(iw1,0.f)*fmaxf(ih1,0.f) > ap3[1]+thr);
        skip2 = skip2 || (fmaxf(iw2,0.f)*fmaxf(ih2,0.f) > ap3[2]+thr);
        skip3 = skip3 || (fmaxf(iw3,0.f)*fmaxf(ih3,0.f) > ap3[3]+thr);
    }
    int cellbase = a*FF + rembase;
    for (int k=0;k<nuse;k++){
        int uc = s_used[k];
        skip0 = skip0 || (uc==cellbase);
        skip1 = skip1 || (uc==cellbase+1);
        skip2 = skip2 || (uc==cellbase+2);
        skip3 = skip3 || (uc==cellbase+3);
    }
    #pragma unroll
    for (int c=0;c<4;c++){
        bool sk = (c==0)?skip0:(c==1)?skip1:(c==2)?skip2:skip3;
        if (c < nc && !sk){
            float snb = sig_neg(co[c]);
            lob += -__logf(fmaxf(snb,1e-7f));
            float ob = 1.0f - snb;
            l2 += ob*ob;
        }
    }
}

__global__ __launch_bounds__(BS) void fused_kernel(
        const float* __restrict__ x0, const float* __restrict__ x1,
        const float* __restrict__ x2, const float* __restrict__ labels,
        unsigned* __restrict__ pay, unsigned* __restrict__ seq,
        float* __restrict__ out)
{
    __shared__ float4 s_bxc[NL];        // cell blocks: compacted valid boxes
    __shared__ float  s_at3c[NL];
    __shared__ int    s_used[NL];
    __shared__ int    s_nuse, s_nbx, s_ntgt;
    __shared__ int    s_code3[3][NL];   // target block: rr | bn<<18 | cls<<20
    __shared__ float  s_tv3[3][NL][5];
    __shared__ int    s_tinfo[NL];      // compacted: rr | aa<<13 | sd<<15 | l<<17
    __shared__ unsigned long long s_tm0[NL], s_tm1[NL];
    __shared__ float  red[5][8];
    __shared__ double dred[5][8];
    __shared__ unsigned s_T;

    const int tid = threadIdx.x;
    const int bxi = blockIdx.x;
    const int b   = blockIdx.y;

    int sid, xoff, tgtblk;
    if      (bxi < NBX0C)       { sid = 0; xoff = bxi;               tgtblk = 0; }
    else if (bxi < NBX0C+NBX1C) { sid = 1; xoff = bxi-NBX0C;         tgtblk = 0; }
    else if (bxi < NBXC)        { sid = 2; xoff = bxi-(NBX0C+NBX1C); tgtblk = 0; }
    else                        { sid = 0; xoff = 0;                 tgtblk = 1; }

    const bool isfin = (bxi == NBXC) && (b == 0);   // batch-0 target block finalizes

    // ---- issue cell loads before prep so latency hides under prep+barrier ----
    float cx[4],cy[4],cw[4],chn[4],co[4];
    int a=0, rembase=0, nc=0;
    bool active=false;
    if (!tgtblk){
        const float* raw = (sid==0)?x0:(sid==1)?x1:x2;
        if      (sid==0) active = cell_load<0>(raw,xoff,b,tid,a,rembase,nc,cx,cy,cw,chn,co);
        else if (sid==1) active = cell_load<1>(raw,xoff,b,tid,a,rembase,nc,cx,cy,cw,chn,co);
        else             active = cell_load<2>(raw,xoff,b,tid,a,rembase,nc,cx,cy,cw,chn,co);
    }

    if (tid == 0){ s_nuse = 0; s_nbx = 0; s_ntgt = 0; }
    __syncthreads();

    if (!tgtblk){
        // ---- cell-block prep: compacted boxes + used-cell list (own scale) ----
        if (tid < NL){
            const float RSTv = (sid==0)?0.125f:(sid==1)?0.0625f:0.03125f;
            const int   F    = (sid==0)?76:(sid==1)?38:19;
            const float* lb = labels + ((size_t)b*NL + tid)*5;
            float x1f=lb[0], y1f=lb[1], x2f=lb[2], y2f=lb[3], cl=lb[4];
            bool valid = (x1f+y1f+x2f+y2f+cl) > 0.0f;
            float tx=(x1f+x2f)*0.5f*RSTv, ty=(y1f+y2f)*0.5f*RSTv;
            float tw=(x2f-x1f)*RSTv, th=(y2f-y1f)*RSTv;
            float at=tw*th;
            float best=-1.0f; int bi=0;
            #pragma unroll
            for (int k=0;k<9;k++){
                float rw=d_AW[k]*RSTv, rh=d_AH[k]*RSTv;
                float mw=fminf(tw,rw), mh=fminf(th,rh);
                float inter=(mw>0.f && mh>0.f)? mw*mh : 0.f;
                float aiou = inter/(at + rw*rh - inter);
                if (aiou > best){ best=aiou; bi=k; }   // first-max = jnp.argmax
            }
            if (valid){
                int p = atomicAdd(&s_nbx, 1);
                float htw=0.5f*tw, hth=0.5f*th;
                s_bxc[p]  = make_float4(tx-htw, tx+htw, ty-hth, ty+hth);
                s_at3c[p] = at*(1.0f/3.0f);
            }
            if (valid && (bi/3 == sid)){
                int bn = bi%3;
                int ii=(int)tx, jj=(int)ty;
                int p = atomicAdd(&s_nuse, 1);
                s_used[p] = (bn*F + jj)*F + ii;       // existence-only
            }
        }
    } else {
        // ---- target-block prep 1: codes + t-values for ALL 3 scales ----
        if (tid < 3*NL){
            int sd = tid/NL, l = tid - sd*NL;
            const float RSTv = (sd==0)?0.125f:(sd==1)?0.0625f:0.03125f;
            const int   F    = (sd==0)?76:(sd==1)?38:19;
            const int   FF   = F*F;
            const float* lb = labels + ((size_t)b*NL + l)*5;
            float x1f=lb[0], y1f=lb[1], x2f=lb[2], y2f=lb[3], cl=lb[4];
            bool valid = (x1f+y1f+x2f+y2f+cl) > 0.0f;
            float tx=(x1f+x2f)*0.5f*RSTv, ty=(y1f+y2f)*0.5f*RSTv;
            float tw=(x2f-x1f)*RSTv, th=(y2f-y1f)*RSTv;
            float at=tw*th;
            float best=-1.0f; int bi=0;
            #pragma unroll
            for (int k=0;k<9;k++){
                float rw=d_AW[k]*RSTv, rh=d_AH[k]*RSTv;
                float mw=fminf(tw,rw), mh=fminf(th,rh);
                float inter=(mw>0.f && mh>0.f)? mw*mh : 0.f;
                float aiou = inter/(at + rw*rh - inter);
                if (aiou > best){ best=aiou; bi=k; }
            }
            int bn = bi%3;
            bool use = valid && (bi/3 == sd);
            int ii=(int)tx, jj=(int)ty;
            int rr = jj*F + ii;                       // in-anchor cell
            s_code3[sd][l] = use ? (rr | (bn<<18) | (((int)cl)<<20)) : -1;
            float aw=d_AW[sd*3+bn]*RSTv, ah=d_AH[sd*3+bn]*RSTv;
            s_tv3[sd][l][0]=tx-(float)ii;
            s_tv3[sd][l][1]=ty-(float)jj;
            s_tv3[sd][l][2]=__logf(__fdividef(tw,aw) + 1e-16f);
            s_tv3[sd][l][3]=__logf(__fdividef(th,ah) + 1e-16f);
            s_tv3[sd][l][4]=sqrtf(2.0f - at/(float)FF);
        }
        __syncthreads();
        // ---- target-block prep 2: owner + class-mask per used cell, compacted ----
        if (tid < 3*NL){
            int sd = tid/NL, l = tid - sd*NL;
            int cd = s_code3[sd][l];
            if (cd >= 0){
                int tcell = cd & 0xFFFFF;             // rr | bn<<18
                int last = -1;
                unsigned long long cm0=0ull, cm1=0ull;
                for (int q=0;q<NL;q++){
                    int cq = s_code3[sd][q];
                    if (cq>=0 && (cq&0xFFFFF)==tcell){
                        last = q; int cc = cq>>20;
                        if (cc<64) cm0 |= 1ull<<cc; else cm1 |= 1ull<<(cc-64);
                    }
                }
                if (last == l){                       // single owner per cell
                    int p = atomicAdd(&s_ntgt, 1);
                    int rr = cd & 0x3FFFF, aa = (cd>>18)&3;
                    s_tinfo[p] = rr | (aa<<13) | (sd<<15) | (l<<17);
                    s_tm0[p] = cm0; s_tm1[p] = cm1;
                }
            }
        }
    }
    __syncthreads();

    float lxy=0.f, lwh=0.f, lob=0.f, lcl=0.f, l2=0.f;

    if (!tgtblk){
        if (active){
            int nuse = s_nuse, nbx = s_nbx;
            if      (sid==0) cell_compute<0>(a,rembase,nc,cx,cy,cw,chn,co,s_bxc,s_at3c,nbx,s_used,nuse,lob,l2);
            else if (sid==1) cell_compute<1>(a,rembase,nc,cx,cy,cw,chn,co,s_bxc,s_at3c,nbx,s_used,nuse,lob,l2);
            else             cell_compute<2>(a,rembase,nc,cx,cy,cw,chn,co,s_bxc,s_at3c,nbx,s_used,nuse,lob,l2);
        }
    } else {
        // ---- compacted target pass: prefetch ALL class loads, then process ----
        const int wv = tid>>6, lane = tid&63;
        const int ntgt = s_ntgt;                     // <= 45
        float P1[8], P2[8], E[8];
        int   info[8];
        #pragma unroll
        for (int kk=0; kk<8; kk++){
            int k = wv + kk*8;
            P1[kk]=0.f; P2[kk]=0.f; E[kk]=0.f; info[kk]=-1;
            if (k < ntgt){
                int in = s_tinfo[k];
                info[kk] = in;
                int rr = in & 0x1FFF, aa = (in>>13)&3, sd = (in>>15)&3;
                const float* raw = (sd==0)?x0:(sd==1)?x1:x2;
                int FF = (sd==0)?5776:(sd==1)?1444:361;
                const float* cb = raw + ((size_t)(b*(NA*85) + aa*85))*FF + rr;
                P1[kk] = cb[(size_t)(5+lane)*FF];
                if (lane < 16) P2[kk] = cb[(size_t)(69+lane)*FF];
                if (lane <  5) E[kk]  = cb[(size_t)lane*FF];
            }
        }
        #pragma unroll
        for (int kk=0; kk<8; kk++){
            int in = info[kk];
            if (in < 0) continue;                    // wave-uniform
            int k  = wv + kk*8;
            int l  = (in>>17)&63, sd = (in>>15)&3;
            unsigned long long cm0 = s_tm0[k], cm1 = s_tm1[k];
            float e0=__shfl(E[kk],0), e1=__shfl(E[kk],1), e2=__shfl(E[kk],2),
                  e3=__shfl(E[kk],3), e4=__shfl(E[kk],4);
            float p1 = sig_pos(P1[kk]);
            float t1v = (((cm0>>lane)&1ull)!=0ull) ? 1.f : 0.f;
            lcl += bcef(p1, t1v);
            float d1 = p1 - t1v; l2 += d1*d1;
            if (lane < 16){
                float p2 = sig_pos(P2[kk]);
                float t2v = (((cm1>>lane)&1ull)!=0ull) ? 1.f : 0.f;
                lcl += bcef(p2, t2v);
                float d2 = p2 - t2v; l2 += d2*d2;
            }
            if (lane == 0){
                float xx=sig_pos(e0), yy=sig_pos(e1), ob=sig_pos(e4);
                float t0=s_tv3[sd][l][0], t1=s_tv3[sd][l][1], t2=s_tv3[sd][l][2],
                      t3=s_tv3[sd][l][3], sc=s_tv3[sd][l][4];
                lxy += sc*sc*(bcef(xx,t0)+bcef(yy,t1));
                float d0=(e2-t2)*sc, dd=(e3-t3)*sc;
                lwh += 0.5f*(d0*d0+dd*dd);
                lob += -__logf(fmaxf(ob,1e-12f));
                float dx=xx-t0, dy=yy-t1, dob=ob-1.f;
                l2  += dx*dx+dy*dy+d0*d0+dd*dd+dob*dob;
            }
        }
    }

    // ---- block reduce (8 waves) ----
    float v0=lxy, v1=lwh, v2=lob, v3=lcl, v4=l2;
    #pragma unroll
    for (int off=32; off>0; off>>=1){
        v0 += __shfl_down(v0, off, 64);
        v1 += __shfl_down(v1, off, 64);
        v2 += __shfl_down(v2, off, 64);
        v3 += __shfl_down(v3, off, 64);
        v4 += __shfl_down(v4, off, 64);
    }
    if ((tid & 63) == 0){
        int w = tid >> 6;
        red[0][w]=v0; red[1][w]=v1; red[2][w]=v2; red[3][w]=v3; red[4][w]=v4;
    }
    __syncthreads();

    // ---- publish: payload (atomicExch, device-coherent) -> fence -> seq++ ----
    // Invariant: all 224 seq words are equal at every call boundary (uniform
    // 0xAA poison / uniform fresh alloc; each call +1 per slot; replays are
    // stream-serialized). Finalizer's target T = its own old+1 matches every
    // slot's post-increment value this call, for ANY uniform start. No init.
    if (tid == 0){
        int slot = b*NBX + bxi;
        #pragma unroll
        for (int c=0;c<5;c++){
            float s = red[c][0]+red[c][1]+red[c][2]+red[c][3]
                    + red[c][4]+red[c][5]+red[c][6]+red[c][7];
            atomicExch(&pay[c*TOTAL_BLOCKS + slot], __float_as_uint(s));
        }
        __threadfence();
        unsigned old = atomicAdd(&seq[slot], 1u);
        if (isfin) s_T = old + 1u;
    }

    if (isfin){
        __syncthreads();                     // broadcast s_T
        const unsigned T = s_T;
        if (tid < TOTAL_BLOCKS){
            while (atomicAdd(&seq[tid], 0u) != T){ __builtin_amdgcn_s_sleep(2); }
        }
        __threadfence();
        double v[5] = {0,0,0,0,0};
        if (tid < TOTAL_BLOCKS){
            #pragma unroll
            for (int c=0;c<5;c++)
                v[c] = (double)__uint_as_float(atomicAdd(&pay[c*TOTAL_BLOCKS + tid], 0u));
        }
        #pragma unroll
        for (int off=32; off>0; off>>=1){
            #pragma unroll
            for (int c=0;c<5;c++) v[c] += __shfl_down(v[c], off, 64);
        }
        if ((tid & 63) == 0){
            int w = tid >> 6;
            #pragma unroll
            for (int c=0;c<5;c++) dred[c][w] = v[c];
        }
        __syncthreads();
        if (tid == 0){
            double s[5];
            #pragma unroll
            for (int c=0;c<5;c++){
                s[c] = 0.0;
                #pragma unroll
                for (int w=0; w<8; w++) s[c] += dred[c][w];
            }
            out[0]=(float)(s[0]+s[1]+s[2]+s[3]);
            out[1]=(float)s[0]; out[2]=(float)s[1]; out[3]=(float)s[2];
            out[4]=(float)s[3]; out[5]=(float)s[4];
        }
    }
}

extern "C" void kernel_launch(void* const* d_in, const int* in_sizes, int n_in,
                              void* d_out, int out_size, void* d_ws, size_t ws_size,
                              hipStream_t stream) {
    const float* x0     = (const float*)d_in[0];
    const float* x1     = (const float*)d_in[1];
    const float* x2     = (const float*)d_in[2];
    const float* labels = (const float*)d_in[3];
    float* out = (float*)d_out;

    unsigned* pay = (unsigned*)d_ws;                       // 5*224*4 = 4480 B
    unsigned* seq = (unsigned*)((char*)d_ws + 4608);       // 224*4 B, 64B-aligned

    fused_kernel<<<dim3(NBX, BB), BS, 0, stream>>>(x0, x1, x2, labels, pay, seq, out);
}

// Round 13
// 24.606 us; speedup vs baseline: 1.2604x; 1.0607x over previous
//
#include <hip/hip_runtime.h>

#define BB 16
#define NL 60
#define NA 3
#define NC 80
#define BS 512

// blocks per batch: 9(s0)+3(s1)+1(s2) cell blocks (4 cells/thread, 512 thr) + 1 target
#define NBX0C 9
#define NBX1C 3
#define NBX2C 1
#define NBXC  (NBX0C+NBX1C+NBX2C)   // 13
#define NBX   (NBXC+1)              // 14
#define TOTAL_BLOCKS (NBX*BB)       // 224

typedef _Float16 h2 __attribute__((ext_vector_type(2)));   // lowers to v_pk_*_f16

__device__ __forceinline__ h2 h2_splat(float v){ _Float16 h=(_Float16)v; h2 r; r[0]=h; r[1]=h; return r; }
__device__ __forceinline__ h2 h2_pack(float a, float b){ h2 r; r[0]=(_Float16)a; r[1]=(_Float16)b; return r; }

__device__ __constant__ float d_AW[9] = {12.f,19.f,40.f,36.f,76.f,72.f,142.f,192.f,459.f};
__device__ __constant__ float d_AH[9] = {16.f,36.f,28.f,75.f,55.f,146.f,110.f,243.f,401.f};

__device__ __forceinline__ float sig_pos(float v){ return __fdividef(1.0f, 1.0f + __expf(-v)); }
__device__ __forceinline__ float sig_neg(float v){ return __fdividef(1.0f, 1.0f + __expf(v)); }
__device__ __forceinline__ float bcef(float p, float t){
    float lp  = __logf(fmaxf(p, 1e-12f));
    float l1p = __logf(1.0f - fminf(p, 1.0f - 1e-7f));
    return -(t*lp + (1.0f - t)*l1p);
}

// ---- issue the channel loads EARLY (before prep+barrier) ----
template<int SID>
__device__ __forceinline__ bool cell_load(const float* __restrict__ raw, int xoff, int b, int tid,
        int &a, int &rembase, int &nc,
        float (&cx)[4], float (&cy)[4], float (&cw)[4], float (&ch)[4], float (&co)[4])
{
    constexpr int F  = (SID==0)?76:(SID==1)?38:19;
    constexpr int FF = F*F;
    int t = xoff*BS + tid;
    if (SID < 2){
        constexpr int NT = 3*FF/4;           // FF divisible by 4 for s0/s1
        if (t >= NT) return false;
        a = t / (FF/4);
        rembase = 4*t - a*FF;
        nc = 4;
        const float* base = raw + ((size_t)(b*(NA*85) + a*85))*FF + rembase;
        float4 q0 = *reinterpret_cast<const float4*>(base);
        float4 q1 = *reinterpret_cast<const float4*>(base +   (size_t)FF);
        float4 q2 = *reinterpret_cast<const float4*>(base + 2*(size_t)FF);
        float4 q3 = *reinterpret_cast<const float4*>(base + 3*(size_t)FF);
        float4 q4 = *reinterpret_cast<const float4*>(base + 4*(size_t)FF);
        cx[0]=q0.x; cx[1]=q0.y; cx[2]=q0.z; cx[3]=q0.w;
        cy[0]=q1.x; cy[1]=q1.y; cy[2]=q1.z; cy[3]=q1.w;
        cw[0]=q2.x; cw[1]=q2.y; cw[2]=q2.z; cw[3]=q2.w;
        ch[0]=q3.x; ch[1]=q3.y; ch[2]=q3.z; ch[3]=q3.w;
        co[0]=q4.x; co[1]=q4.y; co[2]=q4.z; co[3]=q4.w;
    } else {
        constexpr int GPA = (FF+3)/4;        // 91 groups per anchor (361 cells)
        if (t >= 3*GPA) return false;
        a = t / GPA;
        int k = t - a*GPA;
        rembase = 4*k;
        nc = (FF - rembase < 4) ? (FF - rembase) : 4;
        const float* base = raw + ((size_t)(b*(NA*85) + a*85))*FF + rembase;
        #pragma unroll
        for (int c=0;c<4;c++){
            bool v = c < nc;
            cx[c] = v ? base[c]              : 0.f;
            cy[c] = v ? base[(size_t)FF+c]   : 0.f;
            cw[c] = v ? base[2*(size_t)FF+c] : 0.f;
            ch[c] = v ? base[3*(size_t)FF+c] : 0.f;
            co[c] = v ? base[4*(size_t)FF+c] : 0.f;
        }
    }
    return true;
}

// packed-fp16 ignore test: run = max_l ( ai - (ap/3 + at/3) ), skip iff run > 0
template<int SID>
__device__ __forceinline__ void cell_compute(int a, int rembase, int nc,
        const float (&cx)[4], const float (&cy)[4], const float (&cw)[4],
        const float (&ch)[4], const float (&co)[4],
        const h2 (*s_bbh)[4], const h2* s_thr2, int nbx,
        const int* s_used, int nuse,
        float &lob, float &l2)
{
    constexpr int   F   = (SID==0)?76:(SID==1)?38:19;
    constexpr int   FF  = F*F;
    constexpr float RST = (SID==0)?0.125f:(SID==1)?0.0625f:0.03125f;
    float aw = d_AW[SID*3+a]*RST, ah = d_AH[SID*3+a]*RST;
    float plox[4],phix[4],ploy[4],phiy[4],ap3[4];
    #pragma unroll
    for (int c=0;c<4;c++){
        int cel = rembase + c;
        int j = cel / F;                 // compile-time divisor
        int i = cel - j*F;
        float x = sig_pos(cx[c]), y = sig_pos(cy[c]);
        float pw = __expf(cw[c])*aw, ph = __expf(ch[c])*ah;
        float px = x + (float)i, py = y + (float)j;
        float hx = 0.5f*pw, hy = 0.5f*ph;
        plox[c]=px-hx; phix[c]=px+hx; ploy[c]=py-hy; phiy[c]=py+hy;
        // clamp to fp16-safe range: decisions depend on values near thresholds (<~240),
        // huge boxes saturate to 60000 and still compare correctly (finite, no inf/nan)
        ap3[c]=fminf(pw*ph*(1.0f/3.0f), 60000.f);
    }
    // pack cell pairs (0,1) and (2,3)
    h2 plox01=h2_pack(plox[0],plox[1]), plox23=h2_pack(plox[2],plox[3]);
    h2 phix01=h2_pack(phix[0],phix[1]), phix23=h2_pack(phix[2],phix[3]);
    h2 ploy01=h2_pack(ploy[0],ploy[1]), ploy23=h2_pack(ploy[2],ploy[3]);
    h2 phiy01=h2_pack(phiy[0],phiy[1]), phiy23=h2_pack(phiy[2],phiy[3]);
    h2 ap301 =h2_pack(ap3[0], ap3[1]),  ap323 =h2_pack(ap3[2], ap3[3]);
    const h2 zero = h2_splat(0.f);
    h2 run01 = h2_splat(-60000.f), run23 = run01;
    #pragma unroll 2
    for (int l=0;l<nbx;l++){             // compacted: valid labels only
        h2 bbx = s_bbh[l][0];            // splatted (lox,lox)
        h2 bby = s_bbh[l][1];            // (hix,hix)
        h2 bbz = s_bbh[l][2];            // (loy,loy)
        h2 bbw = s_bbh[l][3];            // (hiy,hiy)
        h2 thr = s_thr2[l];              // (at/3, at/3)
        h2 iw0 = __builtin_elementwise_min(phix01,bby) - __builtin_elementwise_max(plox01,bbx);
        h2 ih0 = __builtin_elementwise_min(phiy01,bbw) - __builtin_elementwise_max(ploy01,bbz);
        h2 iw1 = __builtin_elementwise_min(phix23,bby) - __builtin_elementwise_max(plox23,bbx);
        h2 ih1 = __builtin_elementwise_min(phiy23,bbw) - __builtin_elementwise_max(ploy23,bbz);
        iw0 = __builtin_elementwise_max(iw0, zero); ih0 = __builtin_elementwise_max(ih0, zero);
        iw1 = __builtin_elementwise_max(iw1, zero); ih1 = __builtin_elementwise_max(ih1, zero);
        h2 d0 = iw0*ih0 - (ap301 + thr);
        h2 d1 = iw1*ih1 - (ap323 + thr);
        run01 = __builtin_elementwise_max(run01, d0);
        run23 = __builtin_elementwise_max(run23, d1);
    }
    bool skip0 = (float)run01[0] > 0.f;
    bool skip1 = (float)run01[1] > 0.f;
    bool skip2 = (float)run23[0] > 0.f;
    bool skip3 = (float)run23[1] > 0.f;
    int cellbase = a*FF + rembase;
    for (int k=0;k<nuse;k++){
        int uc = s_used[k];
        skip0 = skip0 || (uc==cellbase);
        skip1 = skip1 || (uc==cellbase+1);
        skip2 = skip2 || (uc==cellbase+2);
        skip3 = skip3 || (uc==cellbase+3);
    }
    #pragma unroll
    for (int c=0;c<4;c++){
        bool sk = (c==0)?skip0:(c==1)?skip1:(c==2)?skip2:skip3;
        if (c < nc && !sk){
            float snb = sig_neg(co[c]);
            lob += -__logf(fmaxf(snb,1e-7f));
            float ob = 1.0f - snb;
            l2 += ob*ob;
        }
    }
}

__global__ __launch_bounds__(BS) void fused_kernel(
        const float* __restrict__ x0, const float* __restrict__ x1,
        const float* __restrict__ x2, const float* __restrict__ labels,
        float* __restrict__ part)
{
    __shared__ h2     s_bbh[NL][4];     // cell blocks: compacted splatted fp16 boxes
    __shared__ h2     s_thr2[NL];       // splatted at/3
    __shared__ int    s_used[NL];
    __shared__ int    s_nuse, s_nbx, s_ntgt;
    __shared__ int    s_code3[3][NL];   // target block: rr | bn<<18 | cls<<20
    __shared__ float  s_tv3[3][NL][5];
    __shared__ int    s_tinfo[NL];      // compacted: rr | aa<<13 | sd<<15 | l<<17
    __shared__ unsigned long long s_tm0[NL], s_tm1[NL];
    __shared__ float  red[5][8];

    const int tid = threadIdx.x;
    const int bxi = blockIdx.x;
    const int b   = blockIdx.y;

    int sid, xoff, tgtblk;
    if      (bxi < NBX0C)       { sid = 0; xoff = bxi;               tgtblk = 0; }
    else if (bxi < NBX0C+NBX1C) { sid = 1; xoff = bxi-NBX0C;         tgtblk = 0; }
    else if (bxi < NBXC)        { sid = 2; xoff = bxi-(NBX0C+NBX1C); tgtblk = 0; }
    else                        { sid = 0; xoff = 0;                 tgtblk = 1; }

    // ---- issue cell loads before prep so latency hides under prep+barrier ----
    float cx[4],cy[4],cw[4],chn[4],co[4];
    int a=0, rembase=0, nc=0;
    bool active=false;
    if (!tgtblk){
        const float* raw = (sid==0)?x0:(sid==1)?x1:x2;
        if      (sid==0) active = cell_load<0>(raw,xoff,b,tid,a,rembase,nc,cx,cy,cw,chn,co);
        else if (sid==1) active = cell_load<1>(raw,xoff,b,tid,a,rembase,nc,cx,cy,cw,chn,co);
        else             active = cell_load<2>(raw,xoff,b,tid,a,rembase,nc,cx,cy,cw,chn,co);
    }

    if (tid == 0){ s_nuse = 0; s_nbx = 0; s_ntgt = 0; }
    __syncthreads();

    if (!tgtblk){
        // ---- cell-block prep: compacted fp16 boxes + used-cell list (own scale) ----
        if (tid < NL){
            const float RSTv = (sid==0)?0.125f:(sid==1)?0.0625f:0.03125f;
            const int   F    = (sid==0)?76:(sid==1)?38:19;
            const float* lb = labels + ((size_t)b*NL + tid)*5;
            float x1f=lb[0], y1f=lb[1], x2f=lb[2], y2f=lb[3], cl=lb[4];
            bool valid = (x1f+y1f+x2f+y2f+cl) > 0.0f;
            float tx=(x1f+x2f)*0.5f*RSTv, ty=(y1f+y2f)*0.5f*RSTv;
            float tw=(x2f-x1f)*RSTv, th=(y2f-y1f)*RSTv;
            float at=tw*th;
            float best=-1.0f; int bi=0;
            #pragma unroll
            for (int k=0;k<9;k++){
                float rw=d_AW[k]*RSTv, rh=d_AH[k]*RSTv;
                float mw=fminf(tw,rw), mh=fminf(th,rh);
                float inter=(mw>0.f && mh>0.f)? mw*mh : 0.f;
                float aiou = inter/(at + rw*rh - inter);
                if (aiou > best){ best=aiou; bi=k; }   // first-max = jnp.argmax
            }
            if (valid){
                int p = atomicAdd(&s_nbx, 1);
                float htw=0.5f*tw, hth=0.5f*th;
                s_bbh[p][0] = h2_splat(tx-htw);
                s_bbh[p][1] = h2_splat(tx+htw);
                s_bbh[p][2] = h2_splat(ty-hth);
                s_bbh[p][3] = h2_splat(ty+hth);
                s_thr2[p]   = h2_splat(at*(1.0f/3.0f));
            }
            if (valid && (bi/3 == sid)){
                int bn = bi%3;
                int ii=(int)tx, jj=(int)ty;
                int p = atomicAdd(&s_nuse, 1);
                s_used[p] = (bn*F + jj)*F + ii;       // existence-only
            }
        }
    } else {
        // ---- target-block prep 1: codes + t-values for ALL 3 scales ----
        if (tid < 3*NL){
            int sd = tid/NL, l = tid - sd*NL;
            const float RSTv = (sd==0)?0.125f:(sd==1)?0.0625f:0.03125f;
            const int   F    = (sd==0)?76:(sd==1)?38:19;
            const int   FF   = F*F;
            const float* lb = labels + ((size_t)b*NL + l)*5;
            float x1f=lb[0], y1f=lb[1], x2f=lb[2], y2f=lb[3], cl=lb[4];
            bool valid = (x1f+y1f+x2f+y2f+cl) > 0.0f;
            float tx=(x1f+x2f)*0.5f*RSTv, ty=(y1f+y2f)*0.5f*RSTv;
            float tw=(x2f-x1f)*RSTv, th=(y2f-y1f)*RSTv;
            float at=tw*th;
            float best=-1.0f; int bi=0;
            #pragma unroll
            for (int k=0;k<9;k++){
                float rw=d_AW[k]*RSTv, rh=d_AH[k]*RSTv;
                float mw=fminf(tw,rw), mh=fminf(th,rh);
                float inter=(mw>0.f && mh>0.f)? mw*mh : 0.f;
                float aiou = inter/(at + rw*rh - inter);
                if (aiou > best){ best=aiou; bi=k; }
            }
            int bn = bi%3;
            bool use = valid && (bi/3 == sd);
            int ii=(int)tx, jj=(int)ty;
            int rr = jj*F + ii;                       // in-anchor cell
            s_code3[sd][l] = use ? (rr | (bn<<18) | (((int)cl)<<20)) : -1;
            float aw=d_AW[sd*3+bn]*RSTv, ah=d_AH[sd*3+bn]*RSTv;
            s_tv3[sd][l][0]=tx-(float)ii;
            s_tv3[sd][l][1]=ty-(float)jj;
            s_tv3[sd][l][2]=__logf(__fdividef(tw,aw) + 1e-16f);
            s_tv3[sd][l][3]=__logf(__fdividef(th,ah) + 1e-16f);
            s_tv3[sd][l][4]=sqrtf(2.0f - at/(float)FF);
        }
        __syncthreads();
        // ---- target-block prep 2: owner + class-mask per used cell, compacted ----
        if (tid < 3*NL){
            int sd = tid/NL, l = tid - sd*NL;
            int cd = s_code3[sd][l];
            if (cd >= 0){
                int tcell = cd & 0xFFFFF;             // rr | bn<<18
                int last = -1;
                unsigned long long cm0=0ull, cm1=0ull;
                for (int q=0;q<NL;q++){
                    int cq = s_code3[sd][q];
                    if (cq>=0 && (cq&0xFFFFF)==tcell){
                        last = q; int cc = cq>>20;
                        if (cc<64) cm0 |= 1ull<<cc; else cm1 |= 1ull<<(cc-64);
                    }
                }
                if (last == l){                       // single owner per cell
                    int p = atomicAdd(&s_ntgt, 1);
                    int rr = cd & 0x3FFFF, aa = (cd>>18)&3;
                    s_tinfo[p] = rr | (aa<<13) | (sd<<15) | (l<<17);
                    s_tm0[p] = cm0; s_tm1[p] = cm1;
                }
            }
        }
    }
    __syncthreads();

    float lxy=0.f, lwh=0.f, lob=0.f, lcl=0.f, l2=0.f;

    if (!tgtblk){
        if (active){
            int nuse = s_nuse, nbx = s_nbx;
            if      (sid==0) cell_compute<0>(a,rembase,nc,cx,cy,cw,chn,co,s_bbh,s_thr2,nbx,s_used,nuse,lob,l2);
            else if (sid==1) cell_compute<1>(a,rembase,nc,cx,cy,cw,chn,co,s_bbh,s_thr2,nbx,s_used,nuse,lob,l2);
            else             cell_compute<2>(a,rembase,nc,cx,cy,cw,chn,co,s_bbh,s_thr2,nbx,s_used,nuse,lob,l2);
        }
    } else {
        // ---- compacted target pass: prefetch ALL class loads, then process ----
        const int wv = tid>>6, lane = tid&63;
        const int ntgt = s_ntgt;                     // <= 45
        float P1[8], P2[8], E[8];
        int   info[8];
        #pragma unroll
        for (int kk=0; kk<8; kk++){
            int k = wv + kk*8;
            P1[kk]=0.f; P2[kk]=0.f; E[kk]=0.f; info[kk]=-1;
            if (k < ntgt){
                int in = s_tinfo[k];
                info[kk] = in;
                int rr = in & 0x1FFF, aa = (in>>13)&3, sd = (in>>15)&3;
                const float* raw = (sd==0)?x0:(sd==1)?x1:x2;
                int FF = (sd==0)?5776:(sd==1)?1444:361;
                const float* cb = raw + ((size_t)(b*(NA*85) + aa*85))*FF + rr;
                P1[kk] = cb[(size_t)(5+lane)*FF];
                if (lane < 16) P2[kk] = cb[(size_t)(69+lane)*FF];
                if (lane <  5) E[kk]  = cb[(size_t)lane*FF];
            }
        }
        #pragma unroll
        for (int kk=0; kk<8; kk++){
            int in = info[kk];
            if (in < 0) continue;                    // wave-uniform
            int k  = wv + kk*8;
            int l  = (in>>17)&63, sd = (in>>15)&3;
            unsigned long long cm0 = s_tm0[k], cm1 = s_tm1[k];
            float e0=__shfl(E[kk],0), e1=__shfl(E[kk],1), e2=__shfl(E[kk],2),
                  e3=__shfl(E[kk],3), e4=__shfl(E[kk],4);
            float p1 = sig_pos(P1[kk]);
            float t1v = (((cm0>>lane)&1ull)!=0ull) ? 1.f : 0.f;
            lcl += bcef(p1, t1v);
            float d1 = p1 - t1v; l2 += d1*d1;
            if (lane < 16){
                float p2 = sig_pos(P2[kk]);
                float t2v = (((cm1>>lane)&1ull)!=0ull) ? 1.f : 0.f;
                lcl += bcef(p2, t2v);
                float d2 = p2 - t2v; l2 += d2*d2;
            }
            if (lane == 0){
                float xx=sig_pos(e0), yy=sig_pos(e1), ob=sig_pos(e4);
                float t0=s_tv3[sd][l][0], t1=s_tv3[sd][l][1], t2=s_tv3[sd][l][2],
                      t3=s_tv3[sd][l][3], sc=s_tv3[sd][l][4];
                lxy += sc*sc*(bcef(xx,t0)+bcef(yy,t1));
                float d0=(e2-t2)*sc, dd=(e3-t3)*sc;
                lwh += 0.5f*(d0*d0+dd*dd);
                lob += -__logf(fmaxf(ob,1e-12f));
                float dx=xx-t0, dy=yy-t1, dob=ob-1.f;
                l2  += dx*dx+dy*dy+d0*d0+dd*dd+dob*dob;
            }
        }
    }

    // ---- block reduce (8 waves) -> plain store of this block's 5 partials ----
    float v0=lxy, v1=lwh, v2=lob, v3=lcl, v4=l2;
    #pragma unroll
    for (int off=32; off>0; off>>=1){
        v0 += __shfl_down(v0, off, 64);
        v1 += __shfl_down(v1, off, 64);
        v2 += __shfl_down(v2, off, 64);
        v3 += __shfl_down(v3, off, 64);
        v4 += __shfl_down(v4, off, 64);
    }
    if ((tid & 63) == 0){
        int w = tid >> 6;
        red[0][w]=v0; red[1][w]=v1; red[2][w]=v2; red[3][w]=v3; red[4][w]=v4;
    }
    __syncthreads();
    if (tid == 0){
        int slot = b*NBX + bxi;
        #pragma unroll
        for (int c=0;c<5;c++){
            part[c*TOTAL_BLOCKS + slot] = red[c][0]+red[c][1]+red[c][2]+red[c][3]
                                        + red[c][4]+red[c][5]+red[c][6]+red[c][7];
        }
    }
}

// ---------------- final reduction: 224 partials x 5 comps (kernel boundary = coherence) ----
__global__ __launch_bounds__(256) void fin_kernel(const float* __restrict__ part,
                                                  float* __restrict__ out)
{
    __shared__ double red[5][4];
    int tid = threadIdx.x;
    double v[5] = {0,0,0,0,0};
    if (tid < TOTAL_BLOCKS){
        #pragma unroll
        for (int c=0;c<5;c++) v[c] = (double)part[c*TOTAL_BLOCKS + tid];
    }
    #pragma unroll
    for (int off=32; off>0; off>>=1){
        #pragma unroll
        for (int c=0;c<5;c++) v[c] += __shfl_down(v[c], off, 64);
    }
    if ((tid & 63) == 0){
        int w = tid >> 6;
        #pragma unroll
        for (int c=0;c<5;c++) red[c][w] = v[c];
    }
    __syncthreads();
    if (tid == 0){
        double lxy = red[0][0]+red[0][1]+red[0][2]+red[0][3];
        double lwh = red[1][0]+red[1][1]+red[1][2]+red[1][3];
        double lob = red[2][0]+red[2][1]+red[2][2]+red[2][3];
        double lcl = red[3][0]+red[3][1]+red[3][2]+red[3][3];
        double l2  = red[4][0]+red[4][1]+red[4][2]+red[4][3];
        out[0]=(float)(lxy+lwh+lob+lcl);
        out[1]=(float)lxy; out[2]=(float)lwh; out[3]=(float)lob;
        out[4]=(float)lcl; out[5]=(float)l2;
    }
}

extern "C" void kernel_launch(void* const* d_in, const int* in_sizes, int n_in,
                              void* d_out, int out_size, void* d_ws, size_t ws_size,
                              hipStream_t stream) {
    const float* x0     = (const float*)d_in[0];
    const float* x1     = (const float*)d_in[1];
    const float* x2     = (const float*)d_in[2];
    const float* labels = (const float*)d_in[3];
    float* out = (float*)d_out;

    float* part = (float*)d_ws;   // 5*224*4 = 4480 B, plain-stored each call

    fused_kernel<<<dim3(NBX, BB), BS, 0, stream>>>(x0, x1, x2, labels, part);
    fin_kernel<<<1, 256, 0, stream>>>(part, out);
}

// Round 14
// 24.587 us; speedup vs baseline: 1.2614x; 1.0008x over previous
//
#include <hip/hip_runtime.h>

#define BB 16
#define NL 60
#define NA 3
#define NC 80
#define BS 512

// blocks per batch: 9(s0)+3(s1)+1(s2) cell blocks (4 cells/thread, 512 thr) + 1 target
#define NBX0C 9
#define NBX1C 3
#define NBX2C 1
#define NBXC  (NBX0C+NBX1C+NBX2C)   // 13
#define NBX   (NBXC+1)              // 14
#define TOTAL_BLOCKS (NBX*BB)       // 224

__device__ __constant__ float d_AW[9] = {12.f,19.f,40.f,36.f,76.f,72.f,142.f,192.f,459.f};
__device__ __constant__ float d_AH[9] = {16.f,36.f,28.f,75.f,55.f,146.f,110.f,243.f,401.f};

__device__ __forceinline__ float sig_pos(float v){ return __fdividef(1.0f, 1.0f + __expf(-v)); }
__device__ __forceinline__ float sig_neg(float v){ return __fdividef(1.0f, 1.0f + __expf(v)); }
__device__ __forceinline__ float bcef(float p, float t){
    float lp  = __logf(fmaxf(p, 1e-12f));
    float l1p = __logf(1.0f - fminf(p, 1.0f - 1e-7f));
    return -(t*lp + (1.0f - t)*l1p);
}

// ---- issue the channel loads EARLY (before prep+barrier) ----
template<int SID>
__device__ __forceinline__ bool cell_load(const float* __restrict__ raw, int xoff, int b, int tid,
        int &a, int &rembase, int &nc,
        float (&cx)[4], float (&cy)[4], float (&cw)[4], float (&ch)[4], float (&co)[4])
{
    constexpr int F  = (SID==0)?76:(SID==1)?38:19;
    constexpr int FF = F*F;
    int t = xoff*BS + tid;
    if (SID < 2){
        constexpr int NT = 3*FF/4;           // FF divisible by 4 for s0/s1
        if (t >= NT) return false;
        a = t / (FF/4);
        rembase = 4*t - a*FF;
        nc = 4;
        const float* base = raw + ((size_t)(b*(NA*85) + a*85))*FF + rembase;
        float4 q0 = *reinterpret_cast<const float4*>(base);
        float4 q1 = *reinterpret_cast<const float4*>(base +   (size_t)FF);
        float4 q2 = *reinterpret_cast<const float4*>(base + 2*(size_t)FF);
        float4 q3 = *reinterpret_cast<const float4*>(base + 3*(size_t)FF);
        float4 q4 = *reinterpret_cast<const float4*>(base + 4*(size_t)FF);
        cx[0]=q0.x; cx[1]=q0.y; cx[2]=q0.z; cx[3]=q0.w;
        cy[0]=q1.x; cy[1]=q1.y; cy[2]=q1.z; cy[3]=q1.w;
        cw[0]=q2.x; cw[1]=q2.y; cw[2]=q2.z; cw[3]=q2.w;
        ch[0]=q3.x; ch[1]=q3.y; ch[2]=q3.z; ch[3]=q3.w;
        co[0]=q4.x; co[1]=q4.y; co[2]=q4.z; co[3]=q4.w;
    } else {
        constexpr int GPA = (FF+3)/4;        // 91 groups per anchor (361 cells)
        if (t >= 3*GPA) return false;
        a = t / GPA;
        int k = t - a*GPA;
        rembase = 4*k;
        nc = (FF - rembase < 4) ? (FF - rembase) : 4;
        const float* base = raw + ((size_t)(b*(NA*85) + a*85))*FF + rembase;
        #pragma unroll
        for (int c=0;c<4;c++){
            bool v = c < nc;
            cx[c] = v ? base[c]              : 0.f;
            cy[c] = v ? base[(size_t)FF+c]   : 0.f;
            cw[c] = v ? base[2*(size_t)FF+c] : 0.f;
            ch[c] = v ? base[3*(size_t)FF+c] : 0.f;
            co[c] = v ? base[4*(size_t)FF+c] : 0.f;
        }
    }
    return true;
}

template<int SID>
__device__ __forceinline__ void cell_compute(int a, int rembase, int nc,
        const float (&cx)[4], const float (&cy)[4], const float (&cw)[4],
        const float (&ch)[4], const float (&co)[4],
        const float4* s_bxc, const float* s_at3c, int nbx,
        const int* s_used, int nuse,
        float &lob, float &l2)
{
    constexpr int   F   = (SID==0)?76:(SID==1)?38:19;
    constexpr int   FF  = F*F;
    constexpr float RST = (SID==0)?0.125f:(SID==1)?0.0625f:0.03125f;
    float aw = d_AW[SID*3+a]*RST, ah = d_AH[SID*3+a]*RST;
    float plox[4],phix[4],ploy[4],phiy[4],ap3[4];
    #pragma unroll
    for (int c=0;c<4;c++){
        int cel = rembase + c;
        int j = cel / F;                 // compile-time divisor
        int i = cel - j*F;
        float x = sig_pos(cx[c]), y = sig_pos(cy[c]);
        float pw = __expf(cw[c])*aw, ph = __expf(ch[c])*ah;
        float px = x + (float)i, py = y + (float)j;
        float hx = 0.5f*pw, hy = 0.5f*ph;
        plox[c]=px-hx; phix[c]=px+hx; ploy[c]=py-hy; phiy[c]=py+hy;
        ap3[c]=pw*ph*(1.0f/3.0f);
    }
    bool skip0=false, skip1=false, skip2=false, skip3=false;
    #pragma unroll 2
    for (int l=0;l<nbx;l++){             // compacted: valid labels only
        float4 bb = s_bxc[l];
        float thr = s_at3c[l];
        float iw0 = fminf(phix[0],bb.y)-fmaxf(plox[0],bb.x);
        float ih0 = fminf(phiy[0],bb.w)-fmaxf(ploy[0],bb.z);
        float iw1 = fminf(phix[1],bb.y)-fmaxf(plox[1],bb.x);
        float ih1 = fminf(phiy[1],bb.w)-fmaxf(ploy[1],bb.z);
        float iw2 = fminf(phix[2],bb.y)-fmaxf(plox[2],bb.x);
        float ih2 = fminf(phiy[2],bb.w)-fmaxf(ploy[2],bb.z);
        float iw3 = fminf(phix[3],bb.y)-fmaxf(plox[3],bb.x);
        float ih3 = fminf(phiy[3],bb.w)-fmaxf(ploy[3],bb.z);
        skip0 = skip0 || (fmaxf(iw0,0.f)*fmaxf(ih0,0.f) > ap3[0]+thr);
        skip1 = skip1 || (fmaxf(iw1,0.f)*fmaxf(ih1,0.f) > ap3[1]+thr);
        skip2 = skip2 || (fmaxf(iw2,0.f)*fmaxf(ih2,0.f) > ap3[2]+thr);
        skip3 = skip3 || (fmaxf(iw3,0.f)*fmaxf(ih3,0.f) > ap3[3]+thr);
    }
    int cellbase = a*FF + rembase;
    for (int k=0;k<nuse;k++){
        int uc = s_used[k];
        skip0 = skip0 || (uc==cellbase);
        skip1 = skip1 || (uc==cellbase+1);
        skip2 = skip2 || (uc==cellbase+2);
        skip3 = skip3 || (uc==cellbase+3);
    }
    #pragma unroll
    for (int c=0;c<4;c++){
        bool sk = (c==0)?skip0:(c==1)?skip1:(c==2)?skip2:skip3;
        if (c < nc && !sk){
            float snb = sig_neg(co[c]);
            lob += -__logf(fmaxf(snb,1e-7f));
            float ob = 1.0f - snb;
            l2 += ob*ob;
        }
    }
}

__global__ __launch_bounds__(BS) void fused_kernel(
        const float* __restrict__ x0, const float* __restrict__ x1,
        const float* __restrict__ x2, const float* __restrict__ labels,
        float* __restrict__ part)
{
    __shared__ float4 s_bxc[NL];        // cell blocks: compacted valid boxes
    __shared__ float  s_at3c[NL];
    __shared__ int    s_used[NL];
    __shared__ int    s_nuse, s_nbx, s_ntgt;
    __shared__ int    s_code3[3][NL];   // target block: rr | bn<<18 | cls<<20
    __shared__ float  s_tv3[3][NL][5];
    __shared__ int    s_tinfo[NL];      // compacted: rr | aa<<13 | sd<<15 | l<<17
    __shared__ unsigned long long s_tm0[NL], s_tm1[NL];
    __shared__ float  red[5][8];

    const int tid = threadIdx.x;
    const int bxi = blockIdx.x;
    const int b   = blockIdx.y;

    int sid, xoff, tgtblk;
    if      (bxi < NBX0C)       { sid = 0; xoff = bxi;               tgtblk = 0; }
    else if (bxi < NBX0C+NBX1C) { sid = 1; xoff = bxi-NBX0C;         tgtblk = 0; }
    else if (bxi < NBXC)        { sid = 2; xoff = bxi-(NBX0C+NBX1C); tgtblk = 0; }
    else                        { sid = 0; xoff = 0;                 tgtblk = 1; }

    // ---- issue cell loads before prep so latency hides under prep+barrier ----
    float cx[4],cy[4],cw[4],chn[4],co[4];
    int a=0, rembase=0, nc=0;
    bool active=false;
    if (!tgtblk){
        const float* raw = (sid==0)?x0:(sid==1)?x1:x2;
        if      (sid==0) active = cell_load<0>(raw,xoff,b,tid,a,rembase,nc,cx,cy,cw,chn,co);
        else if (sid==1) active = cell_load<1>(raw,xoff,b,tid,a,rembase,nc,cx,cy,cw,chn,co);
        else             active = cell_load<2>(raw,xoff,b,tid,a,rembase,nc,cx,cy,cw,chn,co);
    }

    if (tid == 0){ s_nuse = 0; s_nbx = 0; s_ntgt = 0; }
    __syncthreads();

    if (!tgtblk){
        // ---- cell-block prep: compacted boxes + used-cell list (own scale) ----
        if (tid < NL){
            const float RSTv = (sid==0)?0.125f:(sid==1)?0.0625f:0.03125f;
            const int   F    = (sid==0)?76:(sid==1)?38:19;
            const float* lb = labels + ((size_t)b*NL + tid)*5;
            float x1f=lb[0], y1f=lb[1], x2f=lb[2], y2f=lb[3], cl=lb[4];
            bool valid = (x1f+y1f+x2f+y2f+cl) > 0.0f;
            float tx=(x1f+x2f)*0.5f*RSTv, ty=(y1f+y2f)*0.5f*RSTv;
            float tw=(x2f-x1f)*RSTv, th=(y2f-y1f)*RSTv;
            float at=tw*th;
            float best=-1.0f; int bi=0;
            #pragma unroll
            for (int k=0;k<9;k++){
                float rw=d_AW[k]*RSTv, rh=d_AH[k]*RSTv;
                float mw=fminf(tw,rw), mh=fminf(th,rh);
                float inter=(mw>0.f && mh>0.f)? mw*mh : 0.f;
                float aiou = inter/(at + rw*rh - inter);
                if (aiou > best){ best=aiou; bi=k; }   // first-max = jnp.argmax
            }
            if (valid){
                int p = atomicAdd(&s_nbx, 1);
                float htw=0.5f*tw, hth=0.5f*th;
                s_bxc[p]  = make_float4(tx-htw, tx+htw, ty-hth, ty+hth);
                s_at3c[p] = at*(1.0f/3.0f);
            }
            if (valid && (bi/3 == sid)){
                int bn = bi%3;
                int ii=(int)tx, jj=(int)ty;
                int p = atomicAdd(&s_nuse, 1);
                s_used[p] = (bn*F + jj)*F + ii;       // existence-only
            }
        }
    } else {
        // ---- target-block prep 1: codes + t-values for ALL 3 scales ----
        if (tid < 3*NL){
            int sd = tid/NL, l = tid - sd*NL;
            const float RSTv = (sd==0)?0.125f:(sd==1)?0.0625f:0.03125f;
            const int   F    = (sd==0)?76:(sd==1)?38:19;
            const int   FF   = F*F;
            const float* lb = labels + ((size_t)b*NL + l)*5;
            float x1f=lb[0], y1f=lb[1], x2f=lb[2], y2f=lb[3], cl=lb[4];
            bool valid = (x1f+y1f+x2f+y2f+cl) > 0.0f;
            float tx=(x1f+x2f)*0.5f*RSTv, ty=(y1f+y2f)*0.5f*RSTv;
            float tw=(x2f-x1f)*RSTv, th=(y2f-y1f)*RSTv;
            float at=tw*th;
            float best=-1.0f; int bi=0;
            #pragma unroll
            for (int k=0;k<9;k++){
                float rw=d_AW[k]*RSTv, rh=d_AH[k]*RSTv;
                float mw=fminf(tw,rw), mh=fminf(th,rh);
                float inter=(mw>0.f && mh>0.f)? mw*mh : 0.f;
                float aiou = inter/(at + rw*rh - inter);
                if (aiou > best){ best=aiou; bi=k; }
            }
            int bn = bi%3;
            bool use = valid && (bi/3 == sd);
            int ii=(int)tx, jj=(int)ty;
            int rr = jj*F + ii;                       // in-anchor cell
            s_code3[sd][l] = use ? (rr | (bn<<18) | (((int)cl)<<20)) : -1;
            float aw=d_AW[sd*3+bn]*RSTv, ah=d_AH[sd*3+bn]*RSTv;
            s_tv3[sd][l][0]=tx-(float)ii;
            s_tv3[sd][l][1]=ty-(float)jj;
            s_tv3[sd][l][2]=__logf(__fdividef(tw,aw) + 1e-16f);
            s_tv3[sd][l][3]=__logf(__fdividef(th,ah) + 1e-16f);
            s_tv3[sd][l][4]=sqrtf(2.0f - at/(float)FF);
        }
        __syncthreads();
        // ---- target-block prep 2: owner + class-mask per used cell, compacted ----
        if (tid < 3*NL){
            int sd = tid/NL, l = tid - sd*NL;
            int cd = s_code3[sd][l];
            if (cd >= 0){
                int tcell = cd & 0xFFFFF;             // rr | bn<<18
                int last = -1;
                unsigned long long cm0=0ull, cm1=0ull;
                for (int q=0;q<NL;q++){
                    int cq = s_code3[sd][q];
                    if (cq>=0 && (cq&0xFFFFF)==tcell){
                        last = q; int cc = cq>>20;
                        if (cc<64) cm0 |= 1ull<<cc; else cm1 |= 1ull<<(cc-64);
                    }
                }
                if (last == l){                       // single owner per cell
                    int p = atomicAdd(&s_ntgt, 1);
                    int rr = cd & 0x3FFFF, aa = (cd>>18)&3;
                    s_tinfo[p] = rr | (aa<<13) | (sd<<15) | (l<<17);
                    s_tm0[p] = cm0; s_tm1[p] = cm1;
                }
            }
        }
    }
    __syncthreads();

    float lxy=0.f, lwh=0.f, lob=0.f, lcl=0.f, l2=0.f;

    if (!tgtblk){
        if (active){
            int nuse = s_nuse, nbx = s_nbx;
            if      (sid==0) cell_compute<0>(a,rembase,nc,cx,cy,cw,chn,co,s_bxc,s_at3c,nbx,s_used,nuse,lob,l2);
            else if (sid==1) cell_compute<1>(a,rembase,nc,cx,cy,cw,chn,co,s_bxc,s_at3c,nbx,s_used,nuse,lob,l2);
            else             cell_compute<2>(a,rembase,nc,cx,cy,cw,chn,co,s_bxc,s_at3c,nbx,s_used,nuse,lob,l2);
        }
    } else {
        // ---- compacted target pass: prefetch ALL class loads, then process ----
        const int wv = tid>>6, lane = tid&63;
        const int ntgt = s_ntgt;                     // <= 45
        float P1[8], P2[8], E[8];
        int   info[8];
        #pragma unroll
        for (int kk=0; kk<8; kk++){
            int k = wv + kk*8;
            P1[kk]=0.f; P2[kk]=0.f; E[kk]=0.f; info[kk]=-1;
            if (k < ntgt){
                int in = s_tinfo[k];
                info[kk] = in;
                int rr = in & 0x1FFF, aa = (in>>13)&3, sd = (in>>15)&3;
                const float* raw = (sd==0)?x0:(sd==1)?x1:x2;
                int FF = (sd==0)?5776:(sd==1)?1444:361;
                const float* cb = raw + ((size_t)(b*(NA*85) + aa*85))*FF + rr;
                P1[kk] = cb[(size_t)(5+lane)*FF];
                if (lane < 16) P2[kk] = cb[(size_t)(69+lane)*FF];
                if (lane <  5) E[kk]  = cb[(size_t)lane*FF];
            }
        }
        #pragma unroll
        for (int kk=0; kk<8; kk++){
            int in = info[kk];
            if (in < 0) continue;                    // wave-uniform
            int k  = wv + kk*8;
            int l  = (in>>17)&63, sd = (in>>15)&3;
            unsigned long long cm0 = s_tm0[k], cm1 = s_tm1[k];
            float e0=__shfl(E[kk],0), e1=__shfl(E[kk],1), e2=__shfl(E[kk],2),
                  e3=__shfl(E[kk],3), e4=__shfl(E[kk],4);
            float p1 = sig_pos(P1[kk]);
            float t1v = (((cm0>>lane)&1ull)!=0ull) ? 1.f : 0.f;
            lcl += bcef(p1, t1v);
            float d1 = p1 - t1v; l2 += d1*d1;
            if (lane < 16){
                float p2 = sig_pos(P2[kk]);
                float t2v = (((cm1>>lane)&1ull)!=0ull) ? 1.f : 0.f;
                lcl += bcef(p2, t2v);
                float d2 = p2 - t2v; l2 += d2*d2;
            }
            if (lane == 0){
                float xx=sig_pos(e0), yy=sig_pos(e1), ob=sig_pos(e4);
                float t0=s_tv3[sd][l][0], t1=s_tv3[sd][l][1], t2=s_tv3[sd][l][2],
                      t3=s_tv3[sd][l][3], sc=s_tv3[sd][l][4];
                lxy += sc*sc*(bcef(xx,t0)+bcef(yy,t1));
                float d0=(e2-t2)*sc, dd=(e3-t3)*sc;
                lwh += 0.5f*(d0*d0+dd*dd);
                lob += -__logf(fmaxf(ob,1e-12f));
                float dx=xx-t0, dy=yy-t1, dob=ob-1.f;
                l2  += dx*dx+dy*dy+d0*d0+dd*dd+dob*dob;
            }
        }
    }

    // ---- block reduce (8 waves) -> plain store of this block's 5 partials ----
    float v0=lxy, v1=lwh, v2=lob, v3=lcl, v4=l2;
    #pragma unroll
    for (int off=32; off>0; off>>=1){
        v0 += __shfl_down(v0, off, 64);
        v1 += __shfl_down(v1, off, 64);
        v2 += __shfl_down(v2, off, 64);
        v3 += __shfl_down(v3, off, 64);
        v4 += __shfl_down(v4, off, 64);
    }
    if ((tid & 63) == 0){
        int w = tid >> 6;
        red[0][w]=v0; red[1][w]=v1; red[2][w]=v2; red[3][w]=v3; red[4][w]=v4;
    }
    __syncthreads();
    if (tid == 0){
        int slot = b*NBX + bxi;
        #pragma unroll
        for (int c=0;c<5;c++){
            part[c*TOTAL_BLOCKS + slot] = red[c][0]+red[c][1]+red[c][2]+red[c][3]
                                        + red[c][4]+red[c][5]+red[c][6]+red[c][7];
        }
    }
}

// ---------------- final reduction: 224 partials x 5 comps (kernel boundary = coherence) ----
__global__ __launch_bounds__(256) void fin_kernel(const float* __restrict__ part,
                                                  float* __restrict__ out)
{
    __shared__ double red[5][4];
    int tid = threadIdx.x;
    double v[5] = {0,0,0,0,0};
    if (tid < TOTAL_BLOCKS){
        #pragma unroll
        for (int c=0;c<5;c++) v[c] = (double)part[c*TOTAL_BLOCKS + tid];
    }
    #pragma unroll
    for (int off=32; off>0; off>>=1){
        #pragma unroll
        for (int c=0;c<5;c++) v[c] += __shfl_down(v[c], off, 64);
    }
    if ((tid & 63) == 0){
        int w = tid >> 6;
        #pragma unroll
        for (int c=0;c<5;c++) red[c][w] = v[c];
    }
    __syncthreads();
    if (tid == 0){
        double lxy = red[0][0]+red[0][1]+red[0][2]+red[0][3];
        double lwh = red[1][0]+red[1][1]+red[1][2]+red[1][3];
        double lob = red[2][0]+red[2][1]+red[2][2]+red[2][3];
        double lcl = red[3][0]+red[3][1]+red[3][2]+red[3][3];
        double l2  = red[4][0]+red[4][1]+red[4][2]+red[4][3];
        out[0]=(float)(lxy+lwh+lob+lcl);
        out[1]=(float)lxy; out[2]=(float)lwh; out[3]=(float)lob;
        out[4]=(float)lcl; out[5]=(float)l2;
    }
}

extern "C" void kernel_launch(void* const* d_in, const int* in_sizes, int n_in,
                              void* d_out, int out_size, void* d_ws, size_t ws_size,
                              hipStream_t stream) {
    const float* x0     = (const float*)d_in[0];
    const float* x1     = (const float*)d_in[1];
    const float* x2     = (const float*)d_in[2];
    const float* labels = (const float*)d_in[3];
    float* out = (float*)d_out;

    float* part = (float*)d_ws;   // 5*224*4 = 4480 B, plain-stored each call

    fused_kernel<<<dim3(NBX, BB), BS, 0, stream>>>(x0, x1, x2, labels, part);
    fin_kernel<<<1, 256, 0, stream>>>(part, out);
}